// Round 7
// baseline (2100.224 us; speedup 1.0000x reference)
//
#include <hip/hip_runtime.h>
#include <math.h>

#define NN 50000
#define NE 800000
#define NCOLS 1088   // 256 q | 256 k | 256 v | 256 qt | 64 skip   (cols are h*64+d order)

typedef long long i64;

// ---------------- edge-index dtype probe + extraction ----------------
__global__ void detect_i64(const int* __restrict__ ei32, int* __restrict__ flag) {
  int i = blockIdx.x * blockDim.x + threadIdx.x;
  if (i < 2048) {
    if (ei32[2 * i + 1] != 0) atomicOr(flag, 1);  // 1 -> data is int32
  }
}

__global__ void extract_edges(const void* __restrict__ ei, const int* __restrict__ flag,
                              int* __restrict__ src32, int* __restrict__ dst32, int ne) {
  int is32 = *flag;
  int i = blockIdx.x * blockDim.x + threadIdx.x;
  int st = gridDim.x * blockDim.x;
  if (is32) {
    const int* p = (const int*)ei;
    for (; i < ne; i += st) { src32[i] = p[i]; dst32[i] = p[ne + i]; }
  } else {
    const i64* p = (const i64*)ei;
    for (; i < ne; i += st) { src32[i] = (int)p[i]; dst32[i] = (int)p[ne + i]; }
  }
}

// ---------------- CSR build ----------------
__global__ void hist_kernel(const int* __restrict__ dst, int* __restrict__ deg, int ne) {
  int i = blockIdx.x * blockDim.x + threadIdx.x;
  int st = gridDim.x * blockDim.x;
  for (; i < ne; i += st) atomicAdd(&deg[dst[i]], 1);
}

__global__ void scan_kernel(const int* __restrict__ deg, int* __restrict__ row_ptr, int n) {
  __shared__ int buf[1024];
  int t = threadIdx.x;
  int carry = 0;
  if (t == 0) row_ptr[0] = 0;
  for (int base = 0; base < n; base += 1024) {
    int v = (base + t < n) ? deg[base + t] : 0;
    buf[t] = v;
    __syncthreads();
    for (int off = 1; off < 1024; off <<= 1) {
      int x = (t >= off) ? buf[t - off] : 0;
      __syncthreads();
      buf[t] += x;
      __syncthreads();
    }
    if (base + t < n) row_ptr[base + t + 1] = carry + buf[t];
    carry += buf[1023];
    __syncthreads();
  }
}

__global__ void scatter_kernel(const int* __restrict__ src, const int* __restrict__ dst,
                               const int* __restrict__ row_ptr, int* __restrict__ cursor,
                               int* __restrict__ src_sorted, int* __restrict__ eid_sorted, int ne) {
  int i = blockIdx.x * blockDim.x + threadIdx.x;
  int st = gridDim.x * blockDim.x;
  for (; i < ne; i += st) {
    int d = dst[i];
    int pos = row_ptr[d] + atomicAdd(&cursor[d], 1);
    src_sorted[pos] = src[i];
    eid_sorted[pos] = i;
  }
}

// Deterministic order: sort each node's edge list by eid.
__global__ void sort_lists(const int* __restrict__ row_ptr, int* __restrict__ src_sorted,
                           int* __restrict__ eid_sorted, int n) {
  int node = blockIdx.x * blockDim.x + threadIdx.x;
  if (node >= n) return;
  int beg = row_ptr[node], end = row_ptr[node + 1];
  for (int a = beg + 1; a < end; ++a) {
    int e = eid_sorted[a], s = src_sorted[a];
    int b = a - 1;
    while (b >= beg && eid_sorted[b] > e) {
      eid_sorted[b + 1] = eid_sorted[b];
      src_sorted[b + 1] = src_sorted[b];
      --b;
    }
    eid_sorted[b + 1] = e; src_sorted[b + 1] = s;
  }
}

// ---------------- degree-descending node order (counting sort, LPT scheduling) ----------------
__global__ void deg_hist256(const int* __restrict__ row_ptr, int* __restrict__ dh, int n) {
  int node = blockIdx.x * blockDim.x + threadIdx.x;
  if (node >= n) return;
  int d = row_ptr[node + 1] - row_ptr[node];
  if (d > 255) d = 255;
  atomicAdd(&dh[d], 1);
}

__global__ void deg_base256(const int* __restrict__ dh, int* __restrict__ dbase) {
  if (threadIdx.x == 0 && blockIdx.x == 0) {
    int run = 0;
    for (int d = 255; d >= 0; --d) { dbase[d] = run; run += dh[d]; }
  }
}

__global__ void deg_scatter256(const int* __restrict__ row_ptr, const int* __restrict__ dbase,
                               int* __restrict__ dcur, int* __restrict__ order, int n) {
  int node = blockIdx.x * blockDim.x + threadIdx.x;
  if (node >= n) return;
  int d = row_ptr[node + 1] - row_ptr[node];
  if (d > 255) d = 255;
  int pos = dbase[d] + atomicAdd(&dcur[d], 1);
  order[pos] = node;
}

// ---------------- weight prep (fp32, head-major cols) ----------------
__global__ void prep_wt(const float* __restrict__ Wq, const float* __restrict__ Wk,
                        const float* __restrict__ Wv, const float* __restrict__ We,
                        const float* __restrict__ Wsk, float* __restrict__ Wt, int fin) {
  int i = blockIdx.x * blockDim.x + threadIdx.x;
  if (i >= NCOLS * fin) return;
  int col = i / fin, k = i % fin;
  float val;
  if (col < 768) {
    const float* W = (col < 256) ? Wq : (col < 512) ? Wk : Wv;
    val = W[k * 256 + (col & 255)];
  } else if (col < 1024) {
    int idx = col - 768; int h = idx >> 6, ce = idx & 63;
    float a = 0.f;
    for (int d = 0; d < 64; ++d) a += Wq[k * 256 + h * 64 + d] * We[ce * 256 + h * 64 + d];
    val = a;
  } else {
    val = Wsk[k * 64 + (col - 1024)];
  }
  Wt[(size_t)col * fin + k] = val;
}

__global__ void prep_bias(const float* __restrict__ bq, const float* __restrict__ bk,
                          const float* __restrict__ bv, const float* __restrict__ We,
                          const float* __restrict__ bsk, float* __restrict__ bb) {
  int col = blockIdx.x * blockDim.x + threadIdx.x;
  if (col >= NCOLS) return;
  float val;
  if (col < 768) {
    const float* b = (col < 256) ? bq : (col < 512) ? bk : bv;
    val = b[col & 255];
  } else if (col < 1024) {
    int idx = col - 768; int h = idx >> 6, ce = idx & 63;
    float a = 0.f;
    for (int d = 0; d < 64; ++d) a += bq[h * 64 + d] * We[ce * 256 + h * 64 + d];
    val = a;
  } else {
    val = bsk[col - 1024];
  }
  bb[col] = val;
}

// ---------------- fp32 node GEMM: out = X[N,fin] @ Wt^T + b ----------------
// Packed outputs: qq_tab[node][512] = q|qt, kv_tab[node][512] = k|v, skip_tab[node][64]
__global__ __launch_bounds__(256) void node_gemm_f32(
    const float* __restrict__ X, const float* __restrict__ Wt, const float* __restrict__ bb,
    float* __restrict__ qq_tab, float* __restrict__ kv_tab,
    float* __restrict__ skip_tab, int n, int fin) {
  __shared__ __align__(16) float Xs[128][68];
  __shared__ __align__(16) float Ws[64][68];
  int tid = threadIdx.x;
  int tx = tid & 15, ty = tid >> 4;
  int m0 = blockIdx.x * 128, c0 = blockIdx.y * 64;
  float acc[8][4];
  #pragma unroll
  for (int i = 0; i < 8; ++i)
    #pragma unroll
    for (int j = 0; j < 4; ++j) acc[i][j] = 0.f;

  for (int k0 = 0; k0 < fin; k0 += 64) {
    #pragma unroll
    for (int p = 0; p < 8; ++p) {
      int r = ty + 16 * p;
      float4 xv = make_float4(0.f, 0.f, 0.f, 0.f);
      if (m0 + r < n) xv = *(const float4*)&X[(size_t)(m0 + r) * fin + k0 + tx * 4];
      *(float4*)&Xs[r][tx * 4] = xv;
    }
    #pragma unroll
    for (int p = 0; p < 4; ++p) {
      int r = ty + 16 * p;
      float4 wv = *(const float4*)&Wt[(size_t)(c0 + r) * fin + k0 + tx * 4];
      *(float4*)&Ws[r][tx * 4] = wv;
    }
    __syncthreads();
    #pragma unroll 4
    for (int kk = 0; kk < 64; kk += 4) {
      float4 a[8], b[4];
      #pragma unroll
      for (int i = 0; i < 8; ++i) a[i] = *(const float4*)&Xs[ty + 16 * i][kk];
      #pragma unroll
      for (int j = 0; j < 4; ++j) b[j] = *(const float4*)&Ws[tx + 16 * j][kk];
      #pragma unroll
      for (int i = 0; i < 8; ++i)
        #pragma unroll
        for (int j = 0; j < 4; ++j) {
          acc[i][j] = fmaf(a[i].x, b[j].x, acc[i][j]);
          acc[i][j] = fmaf(a[i].y, b[j].y, acc[i][j]);
          acc[i][j] = fmaf(a[i].z, b[j].z, acc[i][j]);
          acc[i][j] = fmaf(a[i].w, b[j].w, acc[i][j]);
        }
    }
    __syncthreads();
  }
  #pragma unroll
  for (int j = 0; j < 4; ++j) {
    int col = c0 + tx + 16 * j;
    float bias = bb[col];
    #pragma unroll
    for (int i = 0; i < 8; ++i) {
      int row = m0 + ty + 16 * i;
      if (row >= n) continue;
      float val = acc[i][j] + bias;
      if (col < 256)        qq_tab[(size_t)row * 512 + col] = val;          // q
      else if (col < 768)   kv_tab[(size_t)row * 512 + col - 256] = val;    // k | v
      else if (col < 1024)  qq_tab[(size_t)row * 512 + col - 512] = val;    // qt
      else                  skip_tab[(size_t)row * 64 + col - 1024] = val;
    }
  }
}

// ---------------- fused attention v3: 2 nodes/wave, 8 lanes/head ----------------
// lane = half*32 + h*8 + c8. Lane owns 8 channels (2 float4) of head h.
// Score reduce: shfl_xor 1,2,4 (one chain serves both halves). GN is lane-local.
__global__ __launch_bounds__(256, 4) void attn_kernel_v3(
    const int* __restrict__ order,
    const int* __restrict__ row_ptr, const int* __restrict__ src_sorted,
    const int* __restrict__ eid_sorted, const float* __restrict__ ea,
    const float* __restrict__ qq_tab, const float* __restrict__ kv_tab,
    const float* __restrict__ skip_tab, const float* __restrict__ west,  // = We [64][256]
    const float* __restrict__ gnw, const float* __restrict__ gnb,
    float* __restrict__ out, int n) {
  int tid = threadIdx.x;
  int wave = tid >> 6, lane = tid & 63;
  int half = lane >> 5, h = (lane >> 3) & 3, c8 = lane & 7;
  int ko = h * 16 + c8 * 2;      // float4 offset of this lane's channel chunk in a 256-f row
  int eo = c8 * 2;               // float4 offset in a 64-float ea row
  const float4* qq4 = (const float4*)qq_tab;
  const float4* kv4 = (const float4*)kv_tab;
  const float4* e4p = (const float4*)ea;
  const float4* w4p = (const float4*)west;

  int slot = blockIdx.x * 8 + wave * 2 + half;
  int node = -1, beg = 0, deg = 0;
  if (slot < n) {
    node = order[slot];
    beg = row_ptr[node];
    deg = row_ptr[node + 1] - beg;
  }
  int tmax = deg;
  { int o = __shfl_xor(tmax, 32); tmax = o > tmax ? o : tmax; }

  float4 q4a = make_float4(0.f,0.f,0.f,0.f), q4b = q4a, t4a = q4a, t4b = q4a;
  if (node >= 0) {
    q4a = qq4[(size_t)node * 128 + ko];
    q4b = qq4[(size_t)node * 128 + ko + 1];
    t4a = qq4[(size_t)node * 128 + 64 + ko];
    t4b = qq4[(size_t)node * 128 + 64 + ko + 1];
  }

  float m = -INFINITY, s = 0.f;
  float4 av0 = make_float4(0.f,0.f,0.f,0.f), av1 = av0, aw0 = av0, aw1 = av0;

  // prefetch edge 0 (clamped; clamped loads read real table rows -> always finite)
  float4 Kn0, Kn1, Vn0, Vn1, En0, En1;
  {
    int jc = beg; if (jc > NE - 1) jc = NE - 1;
    int s_ = src_sorted[jc], e_ = eid_sorted[jc];
    const float4* kr = kv4 + (size_t)s_ * 128;
    Kn0 = kr[ko]; Kn1 = kr[ko + 1];
    Vn0 = kr[64 + ko]; Vn1 = kr[64 + ko + 1];
    const float4* er = e4p + (size_t)e_ * 16;
    En0 = er[eo]; En1 = er[eo + 1];
  }

  for (int t = 0; t < tmax; ++t) {
    float4 K0 = Kn0, K1 = Kn1, V0 = Vn0, V1 = Vn1, E0 = En0, E1 = En1;
    {
      int jn = beg + t + 1; if (jn > NE - 1) jn = NE - 1;
      int s_ = src_sorted[jn], e_ = eid_sorted[jn];
      const float4* kr = kv4 + (size_t)s_ * 128;
      Kn0 = kr[ko]; Kn1 = kr[ko + 1];
      Vn0 = kr[64 + ko]; Vn1 = kr[64 + ko + 1];
      const float4* er = e4p + (size_t)e_ * 16;
      En0 = er[eo]; En1 = er[eo + 1];
    }
    float p = q4a.x * K0.x + q4a.y * K0.y + q4a.z * K0.z + q4a.w * K0.w;
    p = fmaf(q4b.x, K1.x, p); p = fmaf(q4b.y, K1.y, p);
    p = fmaf(q4b.z, K1.z, p); p = fmaf(q4b.w, K1.w, p);
    p = fmaf(t4a.x, E0.x, p); p = fmaf(t4a.y, E0.y, p);
    p = fmaf(t4a.z, E0.z, p); p = fmaf(t4a.w, E0.w, p);
    p = fmaf(t4b.x, E1.x, p); p = fmaf(t4b.y, E1.y, p);
    p = fmaf(t4b.z, E1.z, p); p = fmaf(t4b.w, E1.w, p);
    p += __shfl_xor(p, 1);
    p += __shfl_xor(p, 2);
    p += __shfl_xor(p, 4);
    p *= 0.125f;
    bool valid = (t < deg);
    float d_ = p - m;
    float e_ = __expf(-fabsf(d_));
    float sc = (valid && d_ > 0.f) ? e_ : 1.f;
    float pp = valid ? ((d_ > 0.f) ? 1.f : e_) : 0.f;
    if (valid) m = fmaxf(m, p);
    s = s * sc + pp;
    av0.x = av0.x * sc + pp * V0.x; av0.y = av0.y * sc + pp * V0.y;
    av0.z = av0.z * sc + pp * V0.z; av0.w = av0.w * sc + pp * V0.w;
    av1.x = av1.x * sc + pp * V1.x; av1.y = av1.y * sc + pp * V1.y;
    av1.z = av1.z * sc + pp * V1.z; av1.w = av1.w * sc + pp * V1.w;
    aw0.x = aw0.x * sc + pp * E0.x; aw0.y = aw0.y * sc + pp * E0.y;
    aw0.z = aw0.z * sc + pp * E0.z; aw0.w = aw0.w * sc + pp * E0.w;
    aw1.x = aw1.x * sc + pp * E1.x; aw1.y = aw1.y * sc + pp * E1.y;
    aw1.z = aw1.z * sc + pp * E1.z; aw1.w = aw1.w * sc + pp * E1.w;
  }

  float inv = s > 0.f ? 1.f / s : 0.f;
  float4 avn0 = make_float4(av0.x*inv, av0.y*inv, av0.z*inv, av0.w*inv);
  float4 avn1 = make_float4(av1.x*inv, av1.y*inv, av1.z*inv, av1.w*inv);
  float4 awn0 = make_float4(aw0.x*inv, aw0.y*inv, aw0.z*inv, aw0.w*inv);
  float4 awn1 = make_float4(aw1.x*inv, aw1.y*inv, aw1.z*inv, aw1.w*inv);

  // West matvec: post[h][lane's 8 channels] = sum_ce awn[h][ce] * We[ce][h*64 + d]
  float4 post0 = make_float4(0.f,0.f,0.f,0.f), post1 = post0;
  int lbase = lane & 0x38;   // preserve half|h bits
  #pragma unroll
  for (int cc4 = 0; cc4 < 16; ++cc4) {
    float4 srcv = (cc4 & 1) ? awn1 : awn0;
    int sl = lbase | (cc4 >> 1);
    float wa = __shfl(srcv.x, sl);
    float wb = __shfl(srcv.y, sl);
    float wc = __shfl(srcv.z, sl);
    float wd = __shfl(srcv.w, sl);
    const float4* wr = w4p + (size_t)(cc4 * 4) * 64 + ko;
    float4 wA0 = wr[0],   wA1 = wr[1];
    float4 wB0 = wr[64],  wB1 = wr[65];
    float4 wC0 = wr[128], wC1 = wr[129];
    float4 wD0 = wr[192], wD1 = wr[193];
    post0.x = fmaf(wa, wA0.x, post0.x); post0.y = fmaf(wa, wA0.y, post0.y);
    post0.z = fmaf(wa, wA0.z, post0.z); post0.w = fmaf(wa, wA0.w, post0.w);
    post1.x = fmaf(wa, wA1.x, post1.x); post1.y = fmaf(wa, wA1.y, post1.y);
    post1.z = fmaf(wa, wA1.z, post1.z); post1.w = fmaf(wa, wA1.w, post1.w);
    post0.x = fmaf(wb, wB0.x, post0.x); post0.y = fmaf(wb, wB0.y, post0.y);
    post0.z = fmaf(wb, wB0.z, post0.z); post0.w = fmaf(wb, wB0.w, post0.w);
    post1.x = fmaf(wb, wB1.x, post1.x); post1.y = fmaf(wb, wB1.y, post1.y);
    post1.z = fmaf(wb, wB1.z, post1.z); post1.w = fmaf(wb, wB1.w, post1.w);
    post0.x = fmaf(wc, wC0.x, post0.x); post0.y = fmaf(wc, wC0.y, post0.y);
    post0.z = fmaf(wc, wC0.z, post0.z); post0.w = fmaf(wc, wC0.w, post0.w);
    post1.x = fmaf(wc, wC1.x, post1.x); post1.y = fmaf(wc, wC1.y, post1.y);
    post1.z = fmaf(wc, wC1.z, post1.z); post1.w = fmaf(wc, wC1.w, post1.w);
    post0.x = fmaf(wd, wD0.x, post0.x); post0.y = fmaf(wd, wD0.y, post0.y);
    post0.z = fmaf(wd, wD0.z, post0.z); post0.w = fmaf(wd, wD0.w, post0.w);
    post1.x = fmaf(wd, wD1.x, post1.x); post1.y = fmaf(wd, wD1.y, post1.y);
    post1.z = fmaf(wd, wD1.z, post1.z); post1.w = fmaf(wd, wD1.w, post1.w);
  }

  float4 tot0 = make_float4(avn0.x+post0.x, avn0.y+post0.y, avn0.z+post0.z, avn0.w+post0.w);
  float4 tot1 = make_float4(avn1.x+post1.x, avn1.y+post1.y, avn1.z+post1.z, avn1.w+post1.w);
  // head-sum (lanes with same c8, different h): xor 8, 16 (stays within half)
  tot0.x += __shfl_xor(tot0.x, 8);  tot0.y += __shfl_xor(tot0.y, 8);
  tot0.z += __shfl_xor(tot0.z, 8);  tot0.w += __shfl_xor(tot0.w, 8);
  tot1.x += __shfl_xor(tot1.x, 8);  tot1.y += __shfl_xor(tot1.y, 8);
  tot1.z += __shfl_xor(tot1.z, 8);  tot1.w += __shfl_xor(tot1.w, 8);
  tot0.x += __shfl_xor(tot0.x, 16); tot0.y += __shfl_xor(tot0.y, 16);
  tot0.z += __shfl_xor(tot0.z, 16); tot0.w += __shfl_xor(tot0.w, 16);
  tot1.x += __shfl_xor(tot1.x, 16); tot1.y += __shfl_xor(tot1.y, 16);
  tot1.z += __shfl_xor(tot1.z, 16); tot1.w += __shfl_xor(tot1.w, 16);

  if (node >= 0) {
    const float4* skr = (const float4*)(skip_tab + (size_t)node * 64);
    float4 sk0 = skr[c8 * 2], sk1 = skr[c8 * 2 + 1];
    const float4* gwr = (const float4*)gnw;
    const float4* gbr = (const float4*)gnb;
    float4 gw0 = gwr[c8 * 2], gw1 = gwr[c8 * 2 + 1];
    float4 gb0 = gbr[c8 * 2], gb1 = gbr[c8 * 2 + 1];
    // group A = channels c8*8+0..3, group B = +4..7 — lane-local GN
    float a0 = 0.25f * tot0.x + sk0.x, a1 = 0.25f * tot0.y + sk0.y;
    float a2 = 0.25f * tot0.z + sk0.z, a3 = 0.25f * tot0.w + sk0.w;
    float b0 = 0.25f * tot1.x + sk1.x, b1 = 0.25f * tot1.y + sk1.y;
    float b2 = 0.25f * tot1.z + sk1.z, b3 = 0.25f * tot1.w + sk1.w;
    float muA = ((a0 + a1) + (a2 + a3)) * 0.25f;
    float muB = ((b0 + b1) + (b2 + b3)) * 0.25f;
    float dA0 = a0-muA, dA1 = a1-muA, dA2 = a2-muA, dA3 = a3-muA;
    float dB0 = b0-muB, dB1 = b1-muB, dB2 = b2-muB, dB3 = b3-muB;
    float vA = ((dA0*dA0 + dA1*dA1) + (dA2*dA2 + dA3*dA3)) * 0.25f;
    float vB = ((dB0*dB0 + dB1*dB1) + (dB2*dB2 + dB3*dB3)) * 0.25f;
    float rA = rsqrtf(vA + 1e-5f), rB = rsqrtf(vB + 1e-5f);
    float yA0 = dA0*rA*gw0.x + gb0.x, yA1 = dA1*rA*gw0.y + gb0.y;
    float yA2 = dA2*rA*gw0.z + gb0.z, yA3 = dA3*rA*gw0.w + gb0.w;
    float yB0 = dB0*rB*gw1.x + gb1.x, yB1 = dB1*rB*gw1.y + gb1.y;
    float yB2 = dB2*rB*gw1.z + gb1.z, yB3 = dB3*rB*gw1.w + gb1.w;
    #define GELU(y) (0.5f * (y) * (1.0f + erff((y) * 0.70710678118654752f)))
    float gA0 = GELU(yA0), gA1 = GELU(yA1), gA2 = GELU(yA2), gA3 = GELU(yA3);
    float gB0 = GELU(yB0), gB1 = GELU(yB1), gB2 = GELU(yB2), gB3 = GELU(yB3);
    // lane writes channels c8*8 + h*2 + {0,1}
    float ox, oy;
    if (h == 0)      { ox = gA0; oy = gA1; }
    else if (h == 1) { ox = gA2; oy = gA3; }
    else if (h == 2) { ox = gB0; oy = gB1; }
    else             { ox = gB2; oy = gB3; }
    *(float2*)(out + (size_t)node * 64 + c8 * 8 + h * 2) = make_float2(ox, oy);
  }
}

// ---------------- host ----------------
extern "C" void kernel_launch(void* const* d_in, const int* in_sizes, int n_in,
                              void* d_out, int out_size, void* d_ws, size_t ws_size,
                              hipStream_t stream) {
  (void)in_sizes; (void)n_in;
  const float* x = (const float*)d_in[0];
  const void* ei = d_in[1];
  const float* ea = (const float*)d_in[2];
  const float *Wq[3], *bq[3], *Wk[3], *bk[3], *Wv[3], *bv[3], *We[3], *Wsk[3], *bsk[3];
  for (int L = 0; L < 3; ++L) {
    int b = 3 + 9 * L;
    Wq[L] = (const float*)d_in[b + 0]; bq[L] = (const float*)d_in[b + 1];
    Wk[L] = (const float*)d_in[b + 2]; bk[L] = (const float*)d_in[b + 3];
    Wv[L] = (const float*)d_in[b + 4]; bv[L] = (const float*)d_in[b + 5];
    We[L] = (const float*)d_in[b + 6]; Wsk[L] = (const float*)d_in[b + 7];
    bsk[L] = (const float*)d_in[b + 8];
  }
  const float* gnw = (const float*)d_in[30];
  const float* gnb = (const float*)d_in[31];

  char* p = (char*)d_ws;
  auto alloc = [&](size_t bytes) -> void* {
    void* r = (void*)p;
    p += (bytes + 255) & ~(size_t)255;
    return r;
  };
  float* qq_tab = (float*)alloc((size_t)NN * 512 * 4);
  float* kv_tab = (float*)alloc((size_t)NN * 512 * 4);
  float* skip_tab = (float*)alloc((size_t)NN * 64 * 4);
  float* h_buf = (float*)alloc((size_t)NN * 64 * 4);
  int* row_ptr = (int*)alloc((size_t)(NN + 1) * 4);
  int* deg = (int*)alloc((size_t)NN * 4);
  int* cursor = (int*)alloc((size_t)NN * 4);
  int* src_sorted = (int*)alloc((size_t)NE * 4);
  int* eid_sorted = (int*)alloc((size_t)NE * 4);
  int* src32 = (int*)alloc((size_t)NE * 4);
  int* dst32 = (int*)alloc((size_t)NE * 4);
  int* flag = (int*)alloc(256);
  int* dh = (int*)alloc(256 * 4);
  int* dbase = (int*)alloc(256 * 4);
  int* dcur = (int*)alloc(256 * 4);
  int* order = (int*)alloc((size_t)NN * 4);
  float* Wt[3]; float* bb[3];
  Wt[0] = (float*)alloc((size_t)NCOLS * 128 * 4);
  Wt[1] = (float*)alloc((size_t)NCOLS * 64 * 4);
  Wt[2] = (float*)alloc((size_t)NCOLS * 64 * 4);
  for (int L = 0; L < 3; ++L) bb[L] = (float*)alloc((size_t)NCOLS * 4);

  // Workspace overflow guard: all-zero output == error 1.65625 signature.
  if ((size_t)(p - (char*)d_ws) > ws_size) {
    hipMemsetAsync(d_out, 0, (size_t)out_size * 4, stream);
    return;
  }

  hipMemsetAsync(deg, 0, (size_t)NN * 4, stream);
  hipMemsetAsync(cursor, 0, (size_t)NN * 4, stream);
  hipMemsetAsync(flag, 0, 4, stream);
  hipMemsetAsync(dh, 0, 256 * 4, stream);
  hipMemsetAsync(dcur, 0, 256 * 4, stream);

  detect_i64<<<8, 256, 0, stream>>>((const int*)ei, flag);
  extract_edges<<<2048, 256, 0, stream>>>(ei, flag, src32, dst32, NE);

  hist_kernel<<<2048, 256, 0, stream>>>(dst32, deg, NE);
  scan_kernel<<<1, 1024, 0, stream>>>(deg, row_ptr, NN);
  scatter_kernel<<<2048, 256, 0, stream>>>(src32, dst32, row_ptr, cursor, src_sorted, eid_sorted, NE);
  sort_lists<<<(NN + 255) / 256, 256, 0, stream>>>(row_ptr, src_sorted, eid_sorted, NN);

  deg_hist256<<<(NN + 255) / 256, 256, 0, stream>>>(row_ptr, dh, NN);
  deg_base256<<<1, 64, 0, stream>>>(dh, dbase);
  deg_scatter256<<<(NN + 255) / 256, 256, 0, stream>>>(row_ptr, dbase, dcur, order, NN);

  for (int L = 0; L < 3; ++L) {
    int fin = (L == 0) ? 128 : 64;
    prep_wt<<<(NCOLS * fin + 255) / 256, 256, 0, stream>>>(Wq[L], Wk[L], Wv[L], We[L], Wsk[L], Wt[L], fin);
    prep_bias<<<(NCOLS + 255) / 256, 256, 0, stream>>>(bq[L], bk[L], bv[L], We[L], bsk[L], bb[L]);
  }

  const float* hin = x;
  int nblk = (NN + 7) / 8;
  for (int L = 0; L < 3; ++L) {
    int fin = (L == 0) ? 128 : 64;
    dim3 g((NN + 127) / 128, 17);
    node_gemm_f32<<<g, 256, 0, stream>>>(hin, Wt[L], bb[L], qq_tab, kv_tab, skip_tab, NN, fin);
    attn_kernel_v3<<<nblk, 256, 0, stream>>>(
        order, row_ptr, src_sorted, eid_sorted, ea, qq_tab, kv_tab,
        skip_tab, We[L], gnw, gnb,
        (L == 2) ? (float*)d_out : h_buf, NN);
    hin = h_buf;
  }
}

// Round 8
// 1831.752 us; speedup vs baseline: 1.1466x; 1.1466x over previous
//
#include <hip/hip_runtime.h>
#include <math.h>

#define NN 50000
#define NE 800000
#define NCOLS 1088   // 256 q | 256 k | 256 v | 256 qt | 64 skip   (cols are h*64+d order)

typedef long long i64;

// ---------------- edge-index dtype probe + extraction ----------------
__global__ void detect_i64(const int* __restrict__ ei32, int* __restrict__ flag) {
  int i = blockIdx.x * blockDim.x + threadIdx.x;
  if (i < 2048) {
    if (ei32[2 * i + 1] != 0) atomicOr(flag, 1);  // 1 -> data is int32
  }
}

__global__ void extract_edges(const void* __restrict__ ei, const int* __restrict__ flag,
                              int* __restrict__ src32, int* __restrict__ dst32, int ne) {
  int is32 = *flag;
  int i = blockIdx.x * blockDim.x + threadIdx.x;
  int st = gridDim.x * blockDim.x;
  if (is32) {
    const int* p = (const int*)ei;
    for (; i < ne; i += st) { src32[i] = p[i]; dst32[i] = p[ne + i]; }
  } else {
    const i64* p = (const i64*)ei;
    for (; i < ne; i += st) { src32[i] = (int)p[i]; dst32[i] = (int)p[ne + i]; }
  }
}

// ---------------- CSR build ----------------
__global__ void hist_kernel(const int* __restrict__ dst, int* __restrict__ deg, int ne) {
  int i = blockIdx.x * blockDim.x + threadIdx.x;
  int st = gridDim.x * blockDim.x;
  for (; i < ne; i += st) atomicAdd(&deg[dst[i]], 1);
}

// Parallel 2-level scan: A) per-chunk inclusive scan, B) chunk-sum prefix, C) add bases.
#define SCHUNK 1024
__global__ void scanA(const int* __restrict__ deg, int* __restrict__ row_ptr,
                      int* __restrict__ csum, int n) {
  __shared__ int buf[SCHUNK];
  int c = blockIdx.x, t = threadIdx.x;
  int idx = c * SCHUNK + t;
  int v = (idx < n) ? deg[idx] : 0;
  buf[t] = v;
  __syncthreads();
  for (int off = 1; off < SCHUNK; off <<= 1) {
    int x = (t >= off) ? buf[t - off] : 0;
    __syncthreads();
    buf[t] += x;
    __syncthreads();
  }
  if (idx < n) row_ptr[idx + 1] = buf[t];
  if (t == SCHUNK - 1) csum[c] = buf[t];
}

__global__ void scanB(int* __restrict__ csum, int nchunks) {
  if (threadIdx.x == 0 && blockIdx.x == 0) {
    int run = 0;
    for (int c = 0; c < nchunks; ++c) { int v = csum[c]; csum[c] = run; run += v; }
  }
}

__global__ void scanC(int* __restrict__ row_ptr, const int* __restrict__ csum, int n) {
  int c = blockIdx.x, t = threadIdx.x;
  int idx = c * SCHUNK + t;
  if (idx < n) row_ptr[idx + 1] += csum[c];
  if (idx == 0) row_ptr[0] = 0;
}

__global__ void scatter_kernel(const int* __restrict__ src, const int* __restrict__ dst,
                               const int* __restrict__ row_ptr, int* __restrict__ cursor,
                               int* __restrict__ src_sorted, int* __restrict__ eid_sorted, int ne) {
  int i = blockIdx.x * blockDim.x + threadIdx.x;
  int st = gridDim.x * blockDim.x;
  for (; i < ne; i += st) {
    int d = dst[i];
    int pos = row_ptr[d] + atomicAdd(&cursor[d], 1);
    src_sorted[pos] = src[i];
    eid_sorted[pos] = i;
  }
}

// Deterministic order: sort each node's edge list by eid.
__global__ void sort_lists(const int* __restrict__ row_ptr, int* __restrict__ src_sorted,
                           int* __restrict__ eid_sorted, int n) {
  int node = blockIdx.x * blockDim.x + threadIdx.x;
  if (node >= n) return;
  int beg = row_ptr[node], end = row_ptr[node + 1];
  for (int a = beg + 1; a < end; ++a) {
    int e = eid_sorted[a], s = src_sorted[a];
    int b = a - 1;
    while (b >= beg && eid_sorted[b] > e) {
      eid_sorted[b + 1] = eid_sorted[b];
      src_sorted[b + 1] = src_sorted[b];
      --b;
    }
    eid_sorted[b + 1] = e; src_sorted[b + 1] = s;
  }
}

// ---------------- ea pre-gather into CSR order (random read once, streamed 3x later) ----------
__global__ void ea_gather(const int* __restrict__ eid_sorted, const float* __restrict__ ea,
                          float* __restrict__ ea_csr, int ne) {
  long total = (long)ne * 16;
  long st = (long)gridDim.x * blockDim.x;
  for (long i = (long)blockIdx.x * blockDim.x + threadIdx.x; i < total; i += st) {
    int j = (int)(i >> 4);
    int c = (int)(i & 15);
    int e = eid_sorted[j];
    ((float4*)ea_csr)[i] = ((const float4*)ea)[(size_t)e * 16 + c];
  }
}

// ---------------- weight prep (fp32, head-major cols) ----------------
__global__ void prep_wt(const float* __restrict__ Wq, const float* __restrict__ Wk,
                        const float* __restrict__ Wv, const float* __restrict__ We,
                        const float* __restrict__ Wsk, float* __restrict__ Wt, int fin) {
  int i = blockIdx.x * blockDim.x + threadIdx.x;
  if (i >= NCOLS * fin) return;
  int col = i / fin, k = i % fin;
  float val;
  if (col < 768) {
    const float* W = (col < 256) ? Wq : (col < 512) ? Wk : Wv;
    val = W[k * 256 + (col & 255)];
  } else if (col < 1024) {
    int idx = col - 768; int h = idx >> 6, ce = idx & 63;
    float a = 0.f;
    for (int d = 0; d < 64; ++d) a += Wq[k * 256 + h * 64 + d] * We[ce * 256 + h * 64 + d];
    val = a;
  } else {
    val = Wsk[k * 64 + (col - 1024)];
  }
  Wt[(size_t)col * fin + k] = val;
}

__global__ void prep_bias(const float* __restrict__ bq, const float* __restrict__ bk,
                          const float* __restrict__ bv, const float* __restrict__ We,
                          const float* __restrict__ bsk, float* __restrict__ bb) {
  int col = blockIdx.x * blockDim.x + threadIdx.x;
  if (col >= NCOLS) return;
  float val;
  if (col < 768) {
    const float* b = (col < 256) ? bq : (col < 512) ? bk : bv;
    val = b[col & 255];
  } else if (col < 1024) {
    int idx = col - 768; int h = idx >> 6, ce = idx & 63;
    float a = 0.f;
    for (int d = 0; d < 64; ++d) a += bq[h * 64 + d] * We[ce * 256 + h * 64 + d];
    val = a;
  } else {
    val = bsk[col - 1024];
  }
  bb[col] = val;
}

// ---------------- fp32 node GEMM: out = X[N,fin] @ Wt^T + b ----------------
// Packed outputs: qq_tab[node][512] = q|qt, kv_tab[node][512] = k|v, skip_tab[node][64]
__global__ __launch_bounds__(256) void node_gemm_f32(
    const float* __restrict__ X, const float* __restrict__ Wt, const float* __restrict__ bb,
    float* __restrict__ qq_tab, float* __restrict__ kv_tab,
    float* __restrict__ skip_tab, int n, int fin) {
  __shared__ __align__(16) float Xs[128][68];
  __shared__ __align__(16) float Ws[64][68];
  int tid = threadIdx.x;
  int tx = tid & 15, ty = tid >> 4;
  int m0 = blockIdx.x * 128, c0 = blockIdx.y * 64;
  float acc[8][4];
  #pragma unroll
  for (int i = 0; i < 8; ++i)
    #pragma unroll
    for (int j = 0; j < 4; ++j) acc[i][j] = 0.f;

  for (int k0 = 0; k0 < fin; k0 += 64) {
    #pragma unroll
    for (int p = 0; p < 8; ++p) {
      int r = ty + 16 * p;
      float4 xv = make_float4(0.f, 0.f, 0.f, 0.f);
      if (m0 + r < n) xv = *(const float4*)&X[(size_t)(m0 + r) * fin + k0 + tx * 4];
      *(float4*)&Xs[r][tx * 4] = xv;
    }
    #pragma unroll
    for (int p = 0; p < 4; ++p) {
      int r = ty + 16 * p;
      float4 wv = *(const float4*)&Wt[(size_t)(c0 + r) * fin + k0 + tx * 4];
      *(float4*)&Ws[r][tx * 4] = wv;
    }
    __syncthreads();
    #pragma unroll 4
    for (int kk = 0; kk < 64; kk += 4) {
      float4 a[8], b[4];
      #pragma unroll
      for (int i = 0; i < 8; ++i) a[i] = *(const float4*)&Xs[ty + 16 * i][kk];
      #pragma unroll
      for (int j = 0; j < 4; ++j) b[j] = *(const float4*)&Ws[tx + 16 * j][kk];
      #pragma unroll
      for (int i = 0; i < 8; ++i)
        #pragma unroll
        for (int j = 0; j < 4; ++j) {
          acc[i][j] = fmaf(a[i].x, b[j].x, acc[i][j]);
          acc[i][j] = fmaf(a[i].y, b[j].y, acc[i][j]);
          acc[i][j] = fmaf(a[i].z, b[j].z, acc[i][j]);
          acc[i][j] = fmaf(a[i].w, b[j].w, acc[i][j]);
        }
    }
    __syncthreads();
  }
  #pragma unroll
  for (int j = 0; j < 4; ++j) {
    int col = c0 + tx + 16 * j;
    float bias = bb[col];
    #pragma unroll
    for (int i = 0; i < 8; ++i) {
      int row = m0 + ty + 16 * i;
      if (row >= n) continue;
      float val = acc[i][j] + bias;
      if (col < 256)        qq_tab[(size_t)row * 512 + col] = val;          // q
      else if (col < 768)   kv_tab[(size_t)row * 512 + col - 256] = val;    // k | v
      else if (col < 1024)  qq_tab[(size_t)row * 512 + col - 512] = val;    // qt
      else                  skip_tab[(size_t)row * 64 + col - 1024] = val;
    }
  }
}

// ---------------- fused attention v4: 2 nodes/wave, ea streamed in CSR order ----------------
// lane = half*32 + h*8 + c8. Lane owns 8 channels (2 float4) of head h.
__global__ __launch_bounds__(256, 4) void attn_kernel_v4(
    const int* __restrict__ row_ptr, const int* __restrict__ src_sorted,
    const int* __restrict__ eid_sorted, const float* __restrict__ ea,
    const float* __restrict__ ea_csr, int use_csr,
    const float* __restrict__ qq_tab, const float* __restrict__ kv_tab,
    const float* __restrict__ skip_tab, const float* __restrict__ west,  // = We [64][256]
    const float* __restrict__ gnw, const float* __restrict__ gnb,
    float* __restrict__ out, int n) {
  int tid = threadIdx.x;
  int wave = tid >> 6, lane = tid & 63;
  int half = lane >> 5, h = (lane >> 3) & 3, c8 = lane & 7;
  int ko = h * 16 + c8 * 2;      // float4 offset of this lane's channel chunk in a 256-f row
  int eo = c8 * 2;               // float4 offset in a 64-float ea row
  const float4* qq4 = (const float4*)qq_tab;
  const float4* kv4 = (const float4*)kv_tab;
  const float4* e4p = (const float4*)ea;
  const float4* ec4 = (const float4*)ea_csr;
  const float4* w4p = (const float4*)west;

  int node = blockIdx.x * 8 + wave * 2 + half;
  int beg = 0, deg = 0;
  if (node < n) {
    beg = row_ptr[node];
    deg = row_ptr[node + 1] - beg;
  } else {
    node = -1;
  }
  int tmax = deg;
  { int o = __shfl_xor(tmax, 32); tmax = o > tmax ? o : tmax; }

  float4 q4a = make_float4(0.f,0.f,0.f,0.f), q4b = q4a, t4a = q4a, t4b = q4a;
  if (node >= 0) {
    q4a = qq4[(size_t)node * 128 + ko];
    q4b = qq4[(size_t)node * 128 + ko + 1];
    t4a = qq4[(size_t)node * 128 + 64 + ko];
    t4b = qq4[(size_t)node * 128 + 64 + ko + 1];
  }

  float m = -INFINITY, s = 0.f;
  float4 av0 = make_float4(0.f,0.f,0.f,0.f), av1 = av0, aw0 = av0, aw1 = av0;

  // prefetch edge 0 (clamped; clamped loads read real table rows -> always finite)
  float4 Kn0, Kn1, Vn0, Vn1, En0, En1;
  {
    int jc = beg; if (jc > NE - 1) jc = NE - 1;
    int s_ = src_sorted[jc];
    const float4* kr = kv4 + (size_t)s_ * 128;
    Kn0 = kr[ko]; Kn1 = kr[ko + 1];
    Vn0 = kr[64 + ko]; Vn1 = kr[64 + ko + 1];
    if (use_csr) {
      const float4* er = ec4 + (size_t)jc * 16;
      En0 = er[eo]; En1 = er[eo + 1];
    } else {
      int e_ = eid_sorted[jc];
      const float4* er = e4p + (size_t)e_ * 16;
      En0 = er[eo]; En1 = er[eo + 1];
    }
  }

  for (int t = 0; t < tmax; ++t) {
    float4 K0 = Kn0, K1 = Kn1, V0 = Vn0, V1 = Vn1, E0 = En0, E1 = En1;
    {
      int jn = beg + t + 1; if (jn > NE - 1) jn = NE - 1;
      int s_ = src_sorted[jn];
      const float4* kr = kv4 + (size_t)s_ * 128;
      Kn0 = kr[ko]; Kn1 = kr[ko + 1];
      Vn0 = kr[64 + ko]; Vn1 = kr[64 + ko + 1];
      if (use_csr) {
        const float4* er = ec4 + (size_t)jn * 16;
        En0 = er[eo]; En1 = er[eo + 1];
      } else {
        int e_ = eid_sorted[jn];
        const float4* er = e4p + (size_t)e_ * 16;
        En0 = er[eo]; En1 = er[eo + 1];
      }
    }
    float p = q4a.x * K0.x + q4a.y * K0.y + q4a.z * K0.z + q4a.w * K0.w;
    p = fmaf(q4b.x, K1.x, p); p = fmaf(q4b.y, K1.y, p);
    p = fmaf(q4b.z, K1.z, p); p = fmaf(q4b.w, K1.w, p);
    p = fmaf(t4a.x, E0.x, p); p = fmaf(t4a.y, E0.y, p);
    p = fmaf(t4a.z, E0.z, p); p = fmaf(t4a.w, E0.w, p);
    p = fmaf(t4b.x, E1.x, p); p = fmaf(t4b.y, E1.y, p);
    p = fmaf(t4b.z, E1.z, p); p = fmaf(t4b.w, E1.w, p);
    p += __shfl_xor(p, 1);
    p += __shfl_xor(p, 2);
    p += __shfl_xor(p, 4);
    p *= 0.125f;
    bool valid = (t < deg);
    float d_ = p - m;
    float e_ = __expf(-fabsf(d_));
    float sc = (valid && d_ > 0.f) ? e_ : 1.f;
    float pp = valid ? ((d_ > 0.f) ? 1.f : e_) : 0.f;
    if (valid) m = fmaxf(m, p);
    s = s * sc + pp;
    av0.x = av0.x * sc + pp * V0.x; av0.y = av0.y * sc + pp * V0.y;
    av0.z = av0.z * sc + pp * V0.z; av0.w = av0.w * sc + pp * V0.w;
    av1.x = av1.x * sc + pp * V1.x; av1.y = av1.y * sc + pp * V1.y;
    av1.z = av1.z * sc + pp * V1.z; av1.w = av1.w * sc + pp * V1.w;
    aw0.x = aw0.x * sc + pp * E0.x; aw0.y = aw0.y * sc + pp * E0.y;
    aw0.z = aw0.z * sc + pp * E0.z; aw0.w = aw0.w * sc + pp * E0.w;
    aw1.x = aw1.x * sc + pp * E1.x; aw1.y = aw1.y * sc + pp * E1.y;
    aw1.z = aw1.z * sc + pp * E1.z; aw1.w = aw1.w * sc + pp * E1.w;
  }

  float inv = s > 0.f ? 1.f / s : 0.f;
  float4 avn0 = make_float4(av0.x*inv, av0.y*inv, av0.z*inv, av0.w*inv);
  float4 avn1 = make_float4(av1.x*inv, av1.y*inv, av1.z*inv, av1.w*inv);
  float4 awn0 = make_float4(aw0.x*inv, aw0.y*inv, aw0.z*inv, aw0.w*inv);
  float4 awn1 = make_float4(aw1.x*inv, aw1.y*inv, aw1.z*inv, aw1.w*inv);

  // West matvec: post[h][lane's 8 channels] = sum_ce awn[h][ce] * We[ce][h*64 + d]
  float4 post0 = make_float4(0.f,0.f,0.f,0.f), post1 = post0;
  int lbase = lane & 0x38;   // preserve half|h bits
  #pragma unroll
  for (int cc4 = 0; cc4 < 16; ++cc4) {
    float4 srcv = (cc4 & 1) ? awn1 : awn0;
    int sl = lbase | (cc4 >> 1);
    float wa = __shfl(srcv.x, sl);
    float wb = __shfl(srcv.y, sl);
    float wc = __shfl(srcv.z, sl);
    float wd = __shfl(srcv.w, sl);
    const float4* wr = w4p + (size_t)(cc4 * 4) * 64 + ko;
    float4 wA0 = wr[0],   wA1 = wr[1];
    float4 wB0 = wr[64],  wB1 = wr[65];
    float4 wC0 = wr[128], wC1 = wr[129];
    float4 wD0 = wr[192], wD1 = wr[193];
    post0.x = fmaf(wa, wA0.x, post0.x); post0.y = fmaf(wa, wA0.y, post0.y);
    post0.z = fmaf(wa, wA0.z, post0.z); post0.w = fmaf(wa, wA0.w, post0.w);
    post1.x = fmaf(wa, wA1.x, post1.x); post1.y = fmaf(wa, wA1.y, post1.y);
    post1.z = fmaf(wa, wA1.z, post1.z); post1.w = fmaf(wa, wA1.w, post1.w);
    post0.x = fmaf(wb, wB0.x, post0.x); post0.y = fmaf(wb, wB0.y, post0.y);
    post0.z = fmaf(wb, wB0.z, post0.z); post0.w = fmaf(wb, wB0.w, post0.w);
    post1.x = fmaf(wb, wB1.x, post1.x); post1.y = fmaf(wb, wB1.y, post1.y);
    post1.z = fmaf(wb, wB1.z, post1.z); post1.w = fmaf(wb, wB1.w, post1.w);
    post0.x = fmaf(wc, wC0.x, post0.x); post0.y = fmaf(wc, wC0.y, post0.y);
    post0.z = fmaf(wc, wC0.z, post0.z); post0.w = fmaf(wc, wC0.w, post0.w);
    post1.x = fmaf(wc, wC1.x, post1.x); post1.y = fmaf(wc, wC1.y, post1.y);
    post1.z = fmaf(wc, wC1.z, post1.z); post1.w = fmaf(wc, wC1.w, post1.w);
    post0.x = fmaf(wd, wD0.x, post0.x); post0.y = fmaf(wd, wD0.y, post0.y);
    post0.z = fmaf(wd, wD0.z, post0.z); post0.w = fmaf(wd, wD0.w, post0.w);
    post1.x = fmaf(wd, wD1.x, post1.x); post1.y = fmaf(wd, wD1.y, post1.y);
    post1.z = fmaf(wd, wD1.z, post1.z); post1.w = fmaf(wd, wD1.w, post1.w);
  }

  float4 tot0 = make_float4(avn0.x+post0.x, avn0.y+post0.y, avn0.z+post0.z, avn0.w+post0.w);
  float4 tot1 = make_float4(avn1.x+post1.x, avn1.y+post1.y, avn1.z+post1.z, avn1.w+post1.w);
  // head-sum (lanes with same c8, different h): xor 8, 16 (stays within half)
  tot0.x += __shfl_xor(tot0.x, 8);  tot0.y += __shfl_xor(tot0.y, 8);
  tot0.z += __shfl_xor(tot0.z, 8);  tot0.w += __shfl_xor(tot0.w, 8);
  tot1.x += __shfl_xor(tot1.x, 8);  tot1.y += __shfl_xor(tot1.y, 8);
  tot1.z += __shfl_xor(tot1.z, 8);  tot1.w += __shfl_xor(tot1.w, 8);
  tot0.x += __shfl_xor(tot0.x, 16); tot0.y += __shfl_xor(tot0.y, 16);
  tot0.z += __shfl_xor(tot0.z, 16); tot0.w += __shfl_xor(tot0.w, 16);
  tot1.x += __shfl_xor(tot1.x, 16); tot1.y += __shfl_xor(tot1.y, 16);
  tot1.z += __shfl_xor(tot1.z, 16); tot1.w += __shfl_xor(tot1.w, 16);

  if (node >= 0) {
    const float4* skr = (const float4*)(skip_tab + (size_t)node * 64);
    float4 sk0 = skr[c8 * 2], sk1 = skr[c8 * 2 + 1];
    const float4* gwr = (const float4*)gnw;
    const float4* gbr = (const float4*)gnb;
    float4 gw0 = gwr[c8 * 2], gw1 = gwr[c8 * 2 + 1];
    float4 gb0 = gbr[c8 * 2], gb1 = gbr[c8 * 2 + 1];
    // group A = channels c8*8+0..3, group B = +4..7 — lane-local GN
    float a0 = 0.25f * tot0.x + sk0.x, a1 = 0.25f * tot0.y + sk0.y;
    float a2 = 0.25f * tot0.z + sk0.z, a3 = 0.25f * tot0.w + sk0.w;
    float b0 = 0.25f * tot1.x + sk1.x, b1 = 0.25f * tot1.y + sk1.y;
    float b2 = 0.25f * tot1.z + sk1.z, b3 = 0.25f * tot1.w + sk1.w;
    float muA = ((a0 + a1) + (a2 + a3)) * 0.25f;
    float muB = ((b0 + b1) + (b2 + b3)) * 0.25f;
    float dA0 = a0-muA, dA1 = a1-muA, dA2 = a2-muA, dA3 = a3-muA;
    float dB0 = b0-muB, dB1 = b1-muB, dB2 = b2-muB, dB3 = b3-muB;
    float vA = ((dA0*dA0 + dA1*dA1) + (dA2*dA2 + dA3*dA3)) * 0.25f;
    float vB = ((dB0*dB0 + dB1*dB1) + (dB2*dB2 + dB3*dB3)) * 0.25f;
    float rA = rsqrtf(vA + 1e-5f), rB = rsqrtf(vB + 1e-5f);
    float yA0 = dA0*rA*gw0.x + gb0.x, yA1 = dA1*rA*gw0.y + gb0.y;
    float yA2 = dA2*rA*gw0.z + gb0.z, yA3 = dA3*rA*gw0.w + gb0.w;
    float yB0 = dB0*rB*gw1.x + gb1.x, yB1 = dB1*rB*gw1.y + gb1.y;
    float yB2 = dB2*rB*gw1.z + gb1.z, yB3 = dB3*rB*gw1.w + gb1.w;
    #define GELU(y) (0.5f * (y) * (1.0f + erff((y) * 0.70710678118654752f)))
    float gA0 = GELU(yA0), gA1 = GELU(yA1), gA2 = GELU(yA2), gA3 = GELU(yA3);
    float gB0 = GELU(yB0), gB1 = GELU(yB1), gB2 = GELU(yB2), gB3 = GELU(yB3);
    // lane writes channels c8*8 + h*2 + {0,1}
    float ox, oy;
    if (h == 0)      { ox = gA0; oy = gA1; }
    else if (h == 1) { ox = gA2; oy = gA3; }
    else if (h == 2) { ox = gB0; oy = gB1; }
    else             { ox = gB2; oy = gB3; }
    *(float2*)(out + (size_t)node * 64 + c8 * 8 + h * 2) = make_float2(ox, oy);
  }
}

// ---------------- host ----------------
extern "C" void kernel_launch(void* const* d_in, const int* in_sizes, int n_in,
                              void* d_out, int out_size, void* d_ws, size_t ws_size,
                              hipStream_t stream) {
  (void)in_sizes; (void)n_in;
  const float* x = (const float*)d_in[0];
  const void* ei = d_in[1];
  const float* ea = (const float*)d_in[2];
  const float *Wq[3], *bq[3], *Wk[3], *bk[3], *Wv[3], *bv[3], *We[3], *Wsk[3], *bsk[3];
  for (int L = 0; L < 3; ++L) {
    int b = 3 + 9 * L;
    Wq[L] = (const float*)d_in[b + 0]; bq[L] = (const float*)d_in[b + 1];
    Wk[L] = (const float*)d_in[b + 2]; bk[L] = (const float*)d_in[b + 3];
    Wv[L] = (const float*)d_in[b + 4]; bv[L] = (const float*)d_in[b + 5];
    We[L] = (const float*)d_in[b + 6]; Wsk[L] = (const float*)d_in[b + 7];
    bsk[L] = (const float*)d_in[b + 8];
  }
  const float* gnw = (const float*)d_in[30];
  const float* gnb = (const float*)d_in[31];

  char* p = (char*)d_ws;
  auto alloc = [&](size_t bytes) -> void* {
    void* r = (void*)p;
    p += (bytes + 255) & ~(size_t)255;
    return r;
  };
  float* qq_tab = (float*)alloc((size_t)NN * 512 * 4);
  float* kv_tab = (float*)alloc((size_t)NN * 512 * 4);
  float* skip_tab = (float*)alloc((size_t)NN * 64 * 4);
  float* h_buf = (float*)alloc((size_t)NN * 64 * 4);
  int* row_ptr = (int*)alloc((size_t)(NN + 1) * 4);
  int* deg = (int*)alloc((size_t)NN * 4);
  int* cursor = (int*)alloc((size_t)NN * 4);
  int* csum = (int*)alloc(1024 * 4);
  int* src_sorted = (int*)alloc((size_t)NE * 4);
  int* eid_sorted = (int*)alloc((size_t)NE * 4);
  int* src32 = (int*)alloc((size_t)NE * 4);
  int* dst32 = (int*)alloc((size_t)NE * 4);
  int* flag = (int*)alloc(256);
  float* Wt[3]; float* bb[3];
  Wt[0] = (float*)alloc((size_t)NCOLS * 128 * 4);
  Wt[1] = (float*)alloc((size_t)NCOLS * 64 * 4);
  Wt[2] = (float*)alloc((size_t)NCOLS * 64 * 4);
  for (int L = 0; L < 3; ++L) bb[L] = (float*)alloc((size_t)NCOLS * 4);

  // Workspace overflow guard on the REQUIRED buffers:
  // all-zero output == error 1.65625 signature.
  if ((size_t)(p - (char*)d_ws) > ws_size) {
    hipMemsetAsync(d_out, 0, (size_t)out_size * 4, stream);
    return;
  }

  // Optional ea_csr buffer (205 MB): streamed ea reads in the attn loop.
  float* ea_csr = nullptr;
  int use_csr = 0;
  {
    size_t need = (size_t)(p - (char*)d_ws) + (size_t)NE * 64 * 4 + 256;
    if (need <= ws_size) {
      ea_csr = (float*)alloc((size_t)NE * 64 * 4);
      use_csr = 1;
    }
  }

  hipMemsetAsync(deg, 0, (size_t)NN * 4, stream);
  hipMemsetAsync(cursor, 0, (size_t)NN * 4, stream);
  hipMemsetAsync(flag, 0, 4, stream);

  detect_i64<<<8, 256, 0, stream>>>((const int*)ei, flag);
  extract_edges<<<2048, 256, 0, stream>>>(ei, flag, src32, dst32, NE);

  hist_kernel<<<2048, 256, 0, stream>>>(dst32, deg, NE);
  int nchunks = (NN + SCHUNK - 1) / SCHUNK;
  scanA<<<nchunks, SCHUNK, 0, stream>>>(deg, row_ptr, csum, NN);
  scanB<<<1, 64, 0, stream>>>(csum, nchunks);
  scanC<<<nchunks, SCHUNK, 0, stream>>>(row_ptr, csum, NN);
  scatter_kernel<<<2048, 256, 0, stream>>>(src32, dst32, row_ptr, cursor, src_sorted, eid_sorted, NE);
  sort_lists<<<(NN + 255) / 256, 256, 0, stream>>>(row_ptr, src_sorted, eid_sorted, NN);
  if (use_csr)
    ea_gather<<<2048, 256, 0, stream>>>(eid_sorted, ea, ea_csr, NE);

  for (int L = 0; L < 3; ++L) {
    int fin = (L == 0) ? 128 : 64;
    prep_wt<<<(NCOLS * fin + 255) / 256, 256, 0, stream>>>(Wq[L], Wk[L], Wv[L], We[L], Wsk[L], Wt[L], fin);
    prep_bias<<<(NCOLS + 255) / 256, 256, 0, stream>>>(bq[L], bk[L], bv[L], We[L], bsk[L], bb[L]);
  }

  const float* hin = x;
  int nblk = (NN + 7) / 8;
  for (int L = 0; L < 3; ++L) {
    int fin = (L == 0) ? 128 : 64;
    dim3 g((NN + 127) / 128, 17);
    node_gemm_f32<<<g, 256, 0, stream>>>(hin, Wt[L], bb[L], qq_tab, kv_tab, skip_tab, NN, fin);
    attn_kernel_v4<<<nblk, 256, 0, stream>>>(
        row_ptr, src_sorted, eid_sorted, ea, ea_csr, use_csr, qq_tab, kv_tab,
        skip_tab, We[L], gnw, gnb,
        (L == 2) ? (float*)d_out : h_buf, NN);
    hin = h_buf;
  }
}